// Round 4
// baseline (324.775 us; speedup 1.0000x reference)
//
#include <hip/hip_runtime.h>
#include <stdint.h>

typedef float  floatx4 __attribute__((ext_vector_type(4)));
typedef int    intx4   __attribute__((ext_vector_type(4)));
typedef int    intx8   __attribute__((ext_vector_type(8)));   // 32 fp8 bytes

#define AS1 __attribute__((address_space(1)))
#define AS3 __attribute__((address_space(3)))

// ---------------------------------------------------------------------------
// helpers
// ---------------------------------------------------------------------------
// Round v (pre-clamped to [-448,448]) to the e4m3fn grid, RNE. Exact.
__device__ __forceinline__ float quant_e4m3_value(float v) {
  float av = fabsf(v);
  float step, rstep;
  if (av < 0.015625f) {            // below 2^-6: e4m3 subnormal region
    step  = 0.001953125f;          // 2^-9
    rstep = 512.0f;
  } else {
    uint32_t e = __float_as_uint(av) >> 23;            // biased exponent
    step  = __uint_as_float((e - 3u) << 23);           // 2^(E-3)
    rstep = __uint_as_float((257u - e) << 23);         // 2^(3-E)
  }
  return rintf(v * rstep) * step;
}

// Encode an f32 value EXACTLY on the e4m3fn grid into its byte (pure bit math).
__device__ __forceinline__ uint32_t enc_e4m3(float v) {
  uint32_t u = __float_as_uint(v);
  uint32_t s = (u >> 24) & 0x80u;
  float av = fabsf(v);
  uint32_t b;
  if (av < 0.015625f) {                       // subnormal: m = av*2^9 (0..7)
    b = s | (uint32_t)(av * 512.0f);
  } else {
    uint32_t e = ((u >> 23) & 0xffu) - 120u;  // e4m3 exponent field 1..15
    uint32_t m = (u >> 20) & 7u;
    b = s | (e << 3) | m;
  }
  return b;
}

__device__ __forceinline__ uint32_t quant4(float4 v, float s) {
  float a0 = quant_e4m3_value(fminf(fmaxf(v.x / s, -448.0f), 448.0f));
  float a1 = quant_e4m3_value(fminf(fmaxf(v.y / s, -448.0f), 448.0f));
  float a2 = quant_e4m3_value(fminf(fmaxf(v.z / s, -448.0f), 448.0f));
  float a3 = quant_e4m3_value(fminf(fmaxf(v.w / s, -448.0f), 448.0f));
  return enc_e4m3(a0) | (enc_e4m3(a1) << 8) | (enc_e4m3(a2) << 16) |
         (enc_e4m3(a3) << 24);
}

// ---------------------------------------------------------------------------
// Kernel 1: quantize x: clip(x/s,±448) -> e4m3 RNE -> raw bytes.
// 16 elems/thread: 4x float4 in (64B), uint4 out (16B).
// ---------------------------------------------------------------------------
__global__ __launch_bounds__(256) void quantize_x_kernel(
    const float4* __restrict__ x, const float* __restrict__ s_ptr,
    uint4* __restrict__ q, int n16) {
  int i = blockIdx.x * 256 + threadIdx.x;
  if (i >= n16) return;
  const float s = s_ptr[0];
  uint4 o;
  o.x = quant4(x[i * 4 + 0], s);
  o.y = quant4(x[i * 4 + 1], s);
  o.z = quant4(x[i * 4 + 2], s);
  o.w = quant4(x[i * 4 + 3], s);
  q[i] = o;
}

// ---------------------------------------------------------------------------
// Kernel 2: weights -> raw e4m3 bytes [N][K], 16 elems/thread.
// Mode detection inlined per block (first 512B of qw, L2-hot, uniform branch):
//   mode 2: f32 holding e4m3 values; mode 1: bf16; mode 0: raw fp8 bytes.
// ---------------------------------------------------------------------------
__global__ __launch_bounds__(256) void prep_w_kernel(
    const uint8_t* __restrict__ qw, uint4* __restrict__ w8, int n16) {
  const uint32_t* q32 = (const uint32_t*)qw;
  int lane = threadIdx.x & 63;
  uint32_t w0 = q32[lane], w1 = q32[lane + 64];
  bool fa = ((w0 & 0xFFFFFu) == 0u) && ((w1 & 0xFFFFFu) == 0u);
  uint32_t nib = (w0 | (w0 >> 16) | w1 | (w1 >> 16)) & 0xFu;
  unsigned long long ba = __ballot(fa);
  unsigned long long bb = __ballot(nib == 0u);
  int m = (ba == ~0ull) ? 2 : ((bb == ~0ull) ? 1 : 0);

  int i = blockIdx.x * 256 + threadIdx.x;
  if (i >= n16) return;
  uint4 o;
  uint32_t r[4];
  if (m == 1) {                       // bf16 storage: <<16 decode (exact), encode
#pragma unroll
    for (int j = 0; j < 4; ++j) {
      ushort4 u = ((const ushort4*)qw)[i * 4 + j];
      r[j] = enc_e4m3(__uint_as_float((uint32_t)u.x << 16)) |
             (enc_e4m3(__uint_as_float((uint32_t)u.y << 16)) << 8) |
             (enc_e4m3(__uint_as_float((uint32_t)u.z << 16)) << 16) |
             (enc_e4m3(__uint_as_float((uint32_t)u.w << 16)) << 24);
    }
  } else if (m == 2) {                // f32 storage
#pragma unroll
    for (int j = 0; j < 4; ++j) {
      float4 v = ((const float4*)qw)[i * 4 + j];
      r[j] = enc_e4m3(v.x) | (enc_e4m3(v.y) << 8) | (enc_e4m3(v.z) << 16) |
             (enc_e4m3(v.w) << 24);
    }
  } else {                            // raw fp8 bytes: straight copy
    uint4 c = ((const uint4*)qw)[i];
    r[0] = c.x; r[1] = c.y; r[2] = c.z; r[3] = c.w;
  }
  o.x = r[0]; o.y = r[1]; o.z = r[2]; o.w = r[3];
  w8[i] = o;
}

// ---------------------------------------------------------------------------
// Kernel 3: MX-scaled fp8 GEMM — m201-style 8-phase schedule (fp8 adaption).
//   BM=BN=256, BK=128 bytes. 512 thr = 8 waves (2M x 4N); per-wave 128x64 =
//   8x4 frags of mfma_scale_f32_16x16x128_f8f6f4 (e8m0 scale 127 = 1.0).
//   LDS 128 KiB: dbuf x (A 32K + B 32K), each tile split into 2 halves.
//   Per K-tile: 4 phases = C-quadrants (m0n0),(m0n1),(m1n1),(m1n0); each
//   phase {ds_read subtile ; stage 1 half (2 gload_lds) ; barrier ;
//   setprio(1) 8xMFMA setprio(0) ; barrier}. Stage ledger: A-halves of
//   t+1 at ph0/ph1 (into buf^1), B-halves of t+2 at ph2/ph3 (into buf —
//   safe: B last read at ph1, drained before ph1's closing barrier).
//   Single counted wait per tile: vmcnt(4) at ph3 (leaves only B(t+2) in
//   flight; forces A(t+1)+B(t+1) landed). Never vmcnt(0) in steady state.
//   T2 chunk-XOR swizzle (linear gload_lds dest + pre-swizzled global src +
//   swizzled ds_read), T5 setprio, T1 bijective XCD swizzle (512 blocks).
// ---------------------------------------------------------------------------
__global__ __launch_bounds__(512, 2) void gemm_fp8_kernel(
    const uint8_t* __restrict__ A, const uint8_t* __restrict__ B,
    const float* __restrict__ wscale, const float* __restrict__ iscale,
    const float* __restrict__ bias, float* __restrict__ out,
    int M, int N, int K) {
  __shared__ uint8_t lds[131072];   // [0,64K): A dbuf; [64K,128K): B dbuf

  const int tid  = threadIdx.x;
  const int lane = tid & 63;
  const int wave = tid >> 6;

  // T1: XCD swizzle (nwg = 512, % 8 == 0 -> bijective)
  const int nbx = gridDim.x;                 // N/256 = 8
  const int nwg = nbx * gridDim.y;           // 512
  int flat = blockIdx.y * nbx + blockIdx.x;
  flat = (flat & 7) * (nwg >> 3) + (flat >> 3);
  const int bm = flat / nbx;
  const int bn = flat - bm * nbx;

  const int wm = (wave >> 2) * 128;          // 0 / 128
  const int wn = (wave & 3) * 64;            // 0..192
  const int r15 = lane & 15, quad = lane >> 4, k8 = r15 & 7;
  const int posL = ((2 * quad)     ^ k8) << 4;   // swizzled 16B chunk offsets
  const int posH = ((2 * quad + 1) ^ k8) << 4;

  // staging: slot s = tid + j*512 (s<1024): local row rl = s>>3 (0..127 of a
  // half), LDS chunkpos p = s&7, global chunk = p ^ (rl&7) (involution).
  const uint8_t* aS[2]; const uint8_t* bS[2]; uint32_t dOf[2];
#pragma unroll
  for (int j = 0; j < 2; ++j) {
    const int s = tid + j * 512, rl = s >> 3, p = s & 7;
    aS[j] = A + (size_t)(bm * 256 + rl) * K + ((p ^ (rl & 7)) << 4);
    bS[j] = B + (size_t)(bn * 256 + rl) * K + ((p ^ (rl & 7)) << 4);
    dOf[j] = (uint32_t)s << 4;
  }
  const size_t hK = (size_t)128 * K;         // advance 128 rows

#define STG_A(j, h, kb, bf_)                                                   \
  __builtin_amdgcn_global_load_lds(                                            \
      (const AS1 void*)(aS[j] + (h) * hK + (kb)),                              \
      (AS3 void*)(&lds[(bf_) * 32768u + (h) * 16384u + dOf[j]]), 16, 0, 0)
#define STG_B(j, h, kb, bf_)                                                   \
  __builtin_amdgcn_global_load_lds(                                            \
      (const AS1 void*)(bS[j] + (h) * hK + (kb)),                              \
      (AS3 void*)(&lds[65536u + (bf_) * 32768u + (h) * 16384u + dOf[j]]),      \
      16, 0, 0)

  floatx4 acc[8][4];
#pragma unroll
  for (int i = 0; i < 8; ++i)
#pragma unroll
    for (int j = 0; j < 4; ++j) acc[i][j] = (floatx4){0.f, 0.f, 0.f, 0.f};

  const int T = K >> 7;                      // 128-byte K-tiles

  // ----- prologue: A(0),B(0) -> buf0; B(1) -> buf1 ("tile -1 ph2/3") -----
  STG_A(0, 0, 0, 0); STG_A(1, 0, 0, 0); STG_A(0, 1, 0, 0); STG_A(1, 1, 0, 0);
  STG_B(0, 0, 0, 0); STG_B(1, 0, 0, 0); STG_B(0, 1, 0, 0); STG_B(1, 1, 0, 0);
  if (T > 1) {
    STG_B(0, 0, 128, 1); STG_B(1, 0, 128, 1);
    STG_B(0, 1, 128, 1); STG_B(1, 1, 128, 1);
    asm volatile("s_waitcnt vmcnt(4)" ::: "memory");   // A(0)+B(0) landed
  } else {
    asm volatile("s_waitcnt vmcnt(0)" ::: "memory");
  }
  __builtin_amdgcn_sched_barrier(0);
  __builtin_amdgcn_s_barrier();

  for (int t = 0; t < T; ++t) {
    const int cur = t & 1;
    const uint8_t* LA = &lds[cur * 32768u] + (wm + r15) * 128;
    const uint8_t* LB = &lds[65536u + cur * 32768u] + (wn + r15) * 128;
    const int kb1 = (t + 1) << 7, kb2 = (t + 2) << 7;
    const bool sA = (t + 1 < T), sB = (t + 2 < T);
    intx8 af[4], bf[4];

    // ---------- PH0: quadrant (m0, n0) ----------
#pragma unroll
    for (int i = 0; i < 4; ++i) {
      intx4 lo = *(const intx4*)(LA + i * 2048 + posL);
      intx4 hi = *(const intx4*)(LA + i * 2048 + posH);
      af[i] = __builtin_shufflevector(lo, hi, 0, 1, 2, 3, 4, 5, 6, 7);
    }
#pragma unroll
    for (int j = 0; j < 2; ++j) {
      intx4 lo = *(const intx4*)(LB + j * 2048 + posL);
      intx4 hi = *(const intx4*)(LB + j * 2048 + posH);
      bf[j] = __builtin_shufflevector(lo, hi, 0, 1, 2, 3, 4, 5, 6, 7);
    }
    if (sA) { STG_A(0, 0, kb1, cur ^ 1); STG_A(1, 0, kb1, cur ^ 1); }
    __builtin_amdgcn_s_barrier();
    __builtin_amdgcn_s_setprio(1);
#pragma unroll
    for (int i = 0; i < 4; ++i)
#pragma unroll
      for (int j = 0; j < 2; ++j)
        acc[i][j] = __builtin_amdgcn_mfma_scale_f32_16x16x128_f8f6f4(
            af[i], bf[j], acc[i][j], 0, 0, 0, 127, 0, 127);
    __builtin_amdgcn_s_setprio(0);
    __builtin_amdgcn_s_barrier();

    // ---------- PH1: quadrant (m0, n1) ----------
#pragma unroll
    for (int j = 2; j < 4; ++j) {
      intx4 lo = *(const intx4*)(LB + j * 2048 + posL);
      intx4 hi = *(const intx4*)(LB + j * 2048 + posH);
      bf[j] = __builtin_shufflevector(lo, hi, 0, 1, 2, 3, 4, 5, 6, 7);
    }
    if (sA) { STG_A(0, 1, kb1, cur ^ 1); STG_A(1, 1, kb1, cur ^ 1); }
    __builtin_amdgcn_s_barrier();
    __builtin_amdgcn_s_setprio(1);
#pragma unroll
    for (int i = 0; i < 4; ++i)
#pragma unroll
      for (int j = 2; j < 4; ++j)
        acc[i][j] = __builtin_amdgcn_mfma_scale_f32_16x16x128_f8f6f4(
            af[i], bf[j], acc[i][j], 0, 0, 0, 127, 0, 127);
    __builtin_amdgcn_s_setprio(0);
    __builtin_amdgcn_s_barrier();

    // ---------- PH2: quadrant (m1, n1) ----------
#pragma unroll
    for (int i = 0; i < 4; ++i) {
      intx4 lo = *(const intx4*)(LA + 8192 + i * 2048 + posL);
      intx4 hi = *(const intx4*)(LA + 8192 + i * 2048 + posH);
      af[i] = __builtin_shufflevector(lo, hi, 0, 1, 2, 3, 4, 5, 6, 7);
    }
    if (sB) { STG_B(0, 0, kb2, cur); STG_B(1, 0, kb2, cur); }
    __builtin_amdgcn_s_barrier();
    __builtin_amdgcn_s_setprio(1);
#pragma unroll
    for (int i = 0; i < 4; ++i)
#pragma unroll
      for (int j = 2; j < 4; ++j)
        acc[4 + i][j] = __builtin_amdgcn_mfma_scale_f32_16x16x128_f8f6f4(
            af[i], bf[j], acc[4 + i][j], 0, 0, 0, 127, 0, 127);
    __builtin_amdgcn_s_setprio(0);
    __builtin_amdgcn_s_barrier();

    // ---------- PH3: quadrant (m1, n0) ----------
    if (sB) { STG_B(0, 1, kb2, cur); STG_B(1, 1, kb2, cur); }
    __builtin_amdgcn_s_barrier();
    __builtin_amdgcn_s_setprio(1);
#pragma unroll
    for (int i = 0; i < 4; ++i)
#pragma unroll
      for (int j = 0; j < 2; ++j)
        acc[4 + i][j] = __builtin_amdgcn_mfma_scale_f32_16x16x128_f8f6f4(
            af[i], bf[j], acc[4 + i][j], 0, 0, 0, 127, 0, 127);
    __builtin_amdgcn_s_setprio(0);
    // T4 counted drain, once per tile: forces A(t+1)+B(t+1) landed; leaves
    // only B(t+2) (4 loads) in flight.
    if (t + 1 < T) {
      if (t + 2 < T) asm volatile("s_waitcnt vmcnt(4)" ::: "memory");
      else           asm volatile("s_waitcnt vmcnt(0)" ::: "memory");
      __builtin_amdgcn_sched_barrier(0);
    }
    __builtin_amdgcn_s_barrier();
  }

  // epilogue: C/D layout col=lane&15, row=quad*4+reg (verified r1/r3)
  const float sc = wscale[0] * iscale[0];
  const int rq = quad * 4;
#pragma unroll
  for (int jj = 0; jj < 4; ++jj) {
    const int col = bn * 256 + wn + jj * 16 + r15;
    const float bv = bias[col];
#pragma unroll
    for (int mi = 0; mi < 8; ++mi) {
      const int row = bm * 256 + wm + (mi >> 2) * 64 + (mi & 3) * 16 + rq;
      float* o = out + (size_t)row * N + col;
#pragma unroll
      for (int r = 0; r < 4; ++r)
        o[(size_t)r * N] = acc[mi][jj][r] * sc + bv;
    }
  }
#undef STG_A
#undef STG_B
}

// ---------------------------------------------------------------------------
extern "C" void kernel_launch(void* const* d_in, const int* in_sizes, int n_in,
                              void* d_out, int out_size, void* d_ws,
                              size_t ws_size, hipStream_t stream) {
  const float*   x      = (const float*)d_in[0];   // f32 [M,K]
  const uint8_t* qw     = (const uint8_t*)d_in[1]; // detected per-call [N,K]
  const float*   wscale = (const float*)d_in[2];   // f32 scalar
  const float*   iscale = (const float*)d_in[3];   // f32 scalar
  const float*   bias   = (const float*)d_in[4];   // f32 [N]
  float*         out    = (float*)d_out;

  const int N = in_sizes[4];          // 2048
  const int K = in_sizes[1] / N;      // 2048
  const int M = in_sizes[0] / K;      // 16384

  // ws layout: [0, M*K) qx fp8 ; [+, N*K) w8 fp8
  uint8_t* qx = (uint8_t*)d_ws;
  uint8_t* w8 = qx + (size_t)M * K;

  const int nx16 = in_sizes[0] / 16;
  quantize_x_kernel<<<(nx16 + 255) / 256, 256, 0, stream>>>(
      (const float4*)x, iscale, (uint4*)qx, nx16);

  const int nw16 = in_sizes[1] / 16;
  prep_w_kernel<<<(nw16 + 255) / 256, 256, 0, stream>>>(qw, (uint4*)w8, nw16);

  dim3 grid(N / 256, M / 256);
  gemm_fp8_kernel<<<grid, 512, 0, stream>>>(qx, w8, wscale, iscale, bias,
                                            out, M, N, K);
}

// Round 5
// 320.799 us; speedup vs baseline: 1.0124x; 1.0124x over previous
//
#include <hip/hip_runtime.h>
#include <stdint.h>

typedef float  floatx4 __attribute__((ext_vector_type(4)));
typedef int    intx4   __attribute__((ext_vector_type(4)));
typedef int    intx8   __attribute__((ext_vector_type(8)));   // 32 fp8 bytes

#define AS1 __attribute__((address_space(1)))
#define AS3 __attribute__((address_space(3)))

// ---------------------------------------------------------------------------
// helpers
// ---------------------------------------------------------------------------
// Round v (pre-clamped to [-448,448]) to the e4m3fn grid, RNE. Exact.
__device__ __forceinline__ float quant_e4m3_value(float v) {
  float av = fabsf(v);
  float step, rstep;
  if (av < 0.015625f) {            // below 2^-6: e4m3 subnormal region
    step  = 0.001953125f;          // 2^-9
    rstep = 512.0f;
  } else {
    uint32_t e = __float_as_uint(av) >> 23;            // biased exponent
    step  = __uint_as_float((e - 3u) << 23);           // 2^(E-3)
    rstep = __uint_as_float((257u - e) << 23);         // 2^(3-E)
  }
  return rintf(v * rstep) * step;
}

// Encode an f32 value EXACTLY on the e4m3fn grid into its byte (pure bit math).
__device__ __forceinline__ uint32_t enc_e4m3(float v) {
  uint32_t u = __float_as_uint(v);
  uint32_t s = (u >> 24) & 0x80u;
  float av = fabsf(v);
  uint32_t b;
  if (av < 0.015625f) {                       // subnormal: m = av*2^9 (0..7)
    b = s | (uint32_t)(av * 512.0f);
  } else {
    uint32_t e = ((u >> 23) & 0xffu) - 120u;  // e4m3 exponent field 1..15
    uint32_t m = (u >> 20) & 7u;
    b = s | (e << 3) | m;
  }
  return b;
}

__device__ __forceinline__ uint32_t quant4(float4 v, float s) {
  float a0 = quant_e4m3_value(fminf(fmaxf(v.x / s, -448.0f), 448.0f));
  float a1 = quant_e4m3_value(fminf(fmaxf(v.y / s, -448.0f), 448.0f));
  float a2 = quant_e4m3_value(fminf(fmaxf(v.z / s, -448.0f), 448.0f));
  float a3 = quant_e4m3_value(fminf(fmaxf(v.w / s, -448.0f), 448.0f));
  return enc_e4m3(a0) | (enc_e4m3(a1) << 8) | (enc_e4m3(a2) << 16) |
         (enc_e4m3(a3) << 24);
}

// ---------------------------------------------------------------------------
// Kernel 1: quantize x: clip(x/s,±448) -> e4m3 RNE -> raw bytes.
// 16 elems/thread: 4x float4 in (64B), uint4 out (16B).
// ---------------------------------------------------------------------------
__global__ __launch_bounds__(256) void quantize_x_kernel(
    const float4* __restrict__ x, const float* __restrict__ s_ptr,
    uint4* __restrict__ q, int n16) {
  int i = blockIdx.x * 256 + threadIdx.x;
  if (i >= n16) return;
  const float s = s_ptr[0];
  uint4 o;
  o.x = quant4(x[i * 4 + 0], s);
  o.y = quant4(x[i * 4 + 1], s);
  o.z = quant4(x[i * 4 + 2], s);
  o.w = quant4(x[i * 4 + 3], s);
  q[i] = o;
}

// ---------------------------------------------------------------------------
// Kernel 2: weights -> raw e4m3 bytes [N][K], 16 elems/thread.
// Mode detection inlined per block (first 512B of qw, L2-hot, uniform branch):
//   mode 2: f32 holding e4m3 values; mode 1: bf16; mode 0: raw fp8 bytes.
// ---------------------------------------------------------------------------
__global__ __launch_bounds__(256) void prep_w_kernel(
    const uint8_t* __restrict__ qw, uint4* __restrict__ w8, int n16) {
  const uint32_t* q32 = (const uint32_t*)qw;
  int lane = threadIdx.x & 63;
  uint32_t w0 = q32[lane], w1 = q32[lane + 64];
  bool fa = ((w0 & 0xFFFFFu) == 0u) && ((w1 & 0xFFFFFu) == 0u);
  uint32_t nib = (w0 | (w0 >> 16) | w1 | (w1 >> 16)) & 0xFu;
  unsigned long long ba = __ballot(fa);
  unsigned long long bb = __ballot(nib == 0u);
  int m = (ba == ~0ull) ? 2 : ((bb == ~0ull) ? 1 : 0);

  int i = blockIdx.x * 256 + threadIdx.x;
  if (i >= n16) return;
  uint4 o;
  uint32_t r[4];
  if (m == 1) {                       // bf16 storage: <<16 decode (exact), encode
#pragma unroll
    for (int j = 0; j < 4; ++j) {
      ushort4 u = ((const ushort4*)qw)[i * 4 + j];
      r[j] = enc_e4m3(__uint_as_float((uint32_t)u.x << 16)) |
             (enc_e4m3(__uint_as_float((uint32_t)u.y << 16)) << 8) |
             (enc_e4m3(__uint_as_float((uint32_t)u.z << 16)) << 16) |
             (enc_e4m3(__uint_as_float((uint32_t)u.w << 16)) << 24);
    }
  } else if (m == 2) {                // f32 storage
#pragma unroll
    for (int j = 0; j < 4; ++j) {
      float4 v = ((const float4*)qw)[i * 4 + j];
      r[j] = enc_e4m3(v.x) | (enc_e4m3(v.y) << 8) | (enc_e4m3(v.z) << 16) |
             (enc_e4m3(v.w) << 24);
    }
  } else {                            // raw fp8 bytes: straight copy
    uint4 c = ((const uint4*)qw)[i];
    r[0] = c.x; r[1] = c.y; r[2] = c.z; r[3] = c.w;
  }
  o.x = r[0]; o.y = r[1]; o.z = r[2]; o.w = r[3];
  w8[i] = o;
}

// ---------------------------------------------------------------------------
// Kernel 3: MX-scaled fp8 GEMM — 2-barrier balanced-half schedule.
//   BM=BN=256, BK=128 bytes. 512 thr = 8 waves (2M x 4N); per-wave 128x64 =
//   8x4 frags of mfma_scale_f32_16x16x128_f8f6f4 (e8m0 scale 127 = 1.0).
//   LDS 128 KiB: dbuf x (A 32K + B 32K).
//   Per K-tile, 2 barriers only:
//     top:   stage A(t+1) (4 gloads, into buf^1)
//     half0: read bf[0..3] (8 b128) + af m-half0 (8 b128); 16 MFMA (setprio)
//     mid-barrier  (=> every wave's B-reads complete: reads precede own MFMA
//                   issue, which precedes barrier arrival)
//     stage B(t+2) (4 gloads, into cur-B — WAR-safe per above)
//     half1: read af m-half1 (8 b128); 16 MFMA (setprio)
//     end:   vmcnt(4) => A(t+1)+B(t+1) landed, only B(t+2) in flight
//            (never vmcnt(0) in steady state); barrier.
//   Each half = 16 b128 + 16 MFMA: balanced LDS/MFMA demand; compiler
//   fine-interleaves lgkmcnt within a half (vs r4's 8-barrier lockstep).
//   T2 chunk-XOR swizzle (linear gload_lds dest + pre-swizzled global src +
//   swizzled ds_read), T5 setprio, T1 bijective XCD swizzle (512 blocks).
// ---------------------------------------------------------------------------
__global__ __launch_bounds__(512, 2) void gemm_fp8_kernel(
    const uint8_t* __restrict__ A, const uint8_t* __restrict__ B,
    const float* __restrict__ wscale, const float* __restrict__ iscale,
    const float* __restrict__ bias, float* __restrict__ out,
    int M, int N, int K) {
  __shared__ uint8_t lds[131072];   // [0,64K): A dbuf; [64K,128K): B dbuf

  const int tid  = threadIdx.x;
  const int lane = tid & 63;
  const int wave = tid >> 6;

  // T1: XCD swizzle (nwg = 512, % 8 == 0 -> bijective)
  const int nbx = gridDim.x;                 // N/256 = 8
  const int nwg = nbx * gridDim.y;           // 512
  int flat = blockIdx.y * nbx + blockIdx.x;
  flat = (flat & 7) * (nwg >> 3) + (flat >> 3);
  const int bm = flat / nbx;
  const int bn = flat - bm * nbx;

  const int wm = (wave >> 2) * 128;          // 0 / 128
  const int wn = (wave & 3) * 64;            // 0..192
  const int r15 = lane & 15, quad = lane >> 4, k8 = r15 & 7;
  const int posL = ((2 * quad)     ^ k8) << 4;   // swizzled 16B chunk offsets
  const int posH = ((2 * quad + 1) ^ k8) << 4;

  // staging: slot s = tid + j*512 (s<1024): local row rl = s>>3 (0..127 of a
  // half), LDS chunkpos p = s&7, global chunk = p ^ (rl&7) (involution).
  const uint8_t* aS[2]; const uint8_t* bS[2]; uint32_t dOf[2];
#pragma unroll
  for (int j = 0; j < 2; ++j) {
    const int s = tid + j * 512, rl = s >> 3, p = s & 7;
    aS[j] = A + (size_t)(bm * 256 + rl) * K + ((p ^ (rl & 7)) << 4);
    bS[j] = B + (size_t)(bn * 256 + rl) * K + ((p ^ (rl & 7)) << 4);
    dOf[j] = (uint32_t)s << 4;
  }
  const size_t hK = (size_t)128 * K;         // advance 128 rows

#define STG_A(j, h, kb, bf_)                                                   \
  __builtin_amdgcn_global_load_lds(                                            \
      (const AS1 void*)(aS[j] + (h) * hK + (kb)),                              \
      (AS3 void*)(&lds[(bf_) * 32768u + (h) * 16384u + dOf[j]]), 16, 0, 0)
#define STG_B(j, h, kb, bf_)                                                   \
  __builtin_amdgcn_global_load_lds(                                            \
      (const AS1 void*)(bS[j] + (h) * hK + (kb)),                              \
      (AS3 void*)(&lds[65536u + (bf_) * 32768u + (h) * 16384u + dOf[j]]),      \
      16, 0, 0)

  floatx4 acc[8][4];
#pragma unroll
  for (int i = 0; i < 8; ++i)
#pragma unroll
    for (int j = 0; j < 4; ++j) acc[i][j] = (floatx4){0.f, 0.f, 0.f, 0.f};

  const int T = K >> 7;                      // 128-byte K-tiles

  // ----- prologue: A(0),B(0) -> buf0; B(1) -> buf1 -----
  STG_A(0, 0, 0, 0); STG_A(1, 0, 0, 0); STG_A(0, 1, 0, 0); STG_A(1, 1, 0, 0);
  STG_B(0, 0, 0, 0); STG_B(1, 0, 0, 0); STG_B(0, 1, 0, 0); STG_B(1, 1, 0, 0);
  if (T > 1) {
    STG_B(0, 0, 128, 1); STG_B(1, 0, 128, 1);
    STG_B(0, 1, 128, 1); STG_B(1, 1, 128, 1);
    asm volatile("s_waitcnt vmcnt(4)" ::: "memory");   // A(0)+B(0) landed
  } else {
    asm volatile("s_waitcnt vmcnt(0)" ::: "memory");
  }
  __builtin_amdgcn_sched_barrier(0);
  __builtin_amdgcn_s_barrier();

  for (int t = 0; t < T; ++t) {
    const int cur = t & 1;
    const uint8_t* LA = &lds[cur * 32768u] + (wm + r15) * 128;
    const uint8_t* LB = &lds[65536u + cur * 32768u] + (wn + r15) * 128;
    const int kb1 = (t + 1) << 7, kb2 = (t + 2) << 7;
    intx8 af[4], bf[4];

    // top: stage A(t+1) into buf^1 (latency covered by the whole tile)
    if (t + 1 < T) {
      STG_A(0, 0, kb1, cur ^ 1); STG_A(1, 0, kb1, cur ^ 1);
      STG_A(0, 1, kb1, cur ^ 1); STG_A(1, 1, kb1, cur ^ 1);
    }

    // ---------- half 0: all B-frags + A m-half 0, 16 MFMA ----------
#pragma unroll
    for (int j = 0; j < 4; ++j) {
      intx4 lo = *(const intx4*)(LB + j * 2048 + posL);
      intx4 hi = *(const intx4*)(LB + j * 2048 + posH);
      bf[j] = __builtin_shufflevector(lo, hi, 0, 1, 2, 3, 4, 5, 6, 7);
    }
#pragma unroll
    for (int i = 0; i < 4; ++i) {
      intx4 lo = *(const intx4*)(LA + i * 2048 + posL);
      intx4 hi = *(const intx4*)(LA + i * 2048 + posH);
      af[i] = __builtin_shufflevector(lo, hi, 0, 1, 2, 3, 4, 5, 6, 7);
    }
    __builtin_amdgcn_s_setprio(1);
#pragma unroll
    for (int i = 0; i < 4; ++i)
#pragma unroll
      for (int j = 0; j < 4; ++j)
        acc[i][j] = __builtin_amdgcn_mfma_scale_f32_16x16x128_f8f6f4(
            af[i], bf[j], acc[i][j], 0, 0, 0, 127, 0, 127);
    __builtin_amdgcn_s_setprio(0);

    // mid-barrier: all waves' cur-B reads complete -> B(t+2) may overwrite
    __builtin_amdgcn_s_barrier();
    if (t + 2 < T) {
      STG_B(0, 0, kb2, cur); STG_B(1, 0, kb2, cur);
      STG_B(0, 1, kb2, cur); STG_B(1, 1, kb2, cur);
    }

    // ---------- half 1: A m-half 1, 16 MFMA ----------
#pragma unroll
    for (int i = 0; i < 4; ++i) {
      intx4 lo = *(const intx4*)(LA + 8192 + i * 2048 + posL);
      intx4 hi = *(const intx4*)(LA + 8192 + i * 2048 + posH);
      af[i] = __builtin_shufflevector(lo, hi, 0, 1, 2, 3, 4, 5, 6, 7);
    }
    __builtin_amdgcn_s_setprio(1);
#pragma unroll
    for (int i = 0; i < 4; ++i)
#pragma unroll
      for (int j = 0; j < 4; ++j)
        acc[4 + i][j] = __builtin_amdgcn_mfma_scale_f32_16x16x128_f8f6f4(
            af[i], bf[j], acc[4 + i][j], 0, 0, 0, 127, 0, 127);
    __builtin_amdgcn_s_setprio(0);

    // end: counted drain — A(t+1)+B(t+1) landed; only B(t+2) stays in flight
    if (t + 1 < T) {
      if (t + 2 < T) asm volatile("s_waitcnt vmcnt(4)" ::: "memory");
      else           asm volatile("s_waitcnt vmcnt(0)" ::: "memory");
      __builtin_amdgcn_sched_barrier(0);
      __builtin_amdgcn_s_barrier();
    }
  }

  // epilogue: C/D layout col=lane&15, row=quad*4+reg (verified r1/r3/r4)
  const float sc = wscale[0] * iscale[0];
  const int rq = quad * 4;
#pragma unroll
  for (int jj = 0; jj < 4; ++jj) {
    const int col = bn * 256 + wn + jj * 16 + r15;
    const float bv = bias[col];
#pragma unroll
    for (int mi = 0; mi < 8; ++mi) {
      const int row = bm * 256 + wm + (mi >> 2) * 64 + (mi & 3) * 16 + rq;
      float* o = out + (size_t)row * N + col;
#pragma unroll
      for (int r = 0; r < 4; ++r)
        o[(size_t)r * N] = acc[mi][jj][r] * sc + bv;
    }
  }
#undef STG_A
#undef STG_B
}

// ---------------------------------------------------------------------------
extern "C" void kernel_launch(void* const* d_in, const int* in_sizes, int n_in,
                              void* d_out, int out_size, void* d_ws,
                              size_t ws_size, hipStream_t stream) {
  const float*   x      = (const float*)d_in[0];   // f32 [M,K]
  const uint8_t* qw     = (const uint8_t*)d_in[1]; // detected per-call [N,K]
  const float*   wscale = (const float*)d_in[2];   // f32 scalar
  const float*   iscale = (const float*)d_in[3];   // f32 scalar
  const float*   bias   = (const float*)d_in[4];   // f32 [N]
  float*         out    = (float*)d_out;

  const int N = in_sizes[4];          // 2048
  const int K = in_sizes[1] / N;      // 2048
  const int M = in_sizes[0] / K;      // 16384

  // ws layout: [0, M*K) qx fp8 ; [+, N*K) w8 fp8
  uint8_t* qx = (uint8_t*)d_ws;
  uint8_t* w8 = qx + (size_t)M * K;

  const int nx16 = in_sizes[0] / 16;
  quantize_x_kernel<<<(nx16 + 255) / 256, 256, 0, stream>>>(
      (const float4*)x, iscale, (uint4*)qx, nx16);

  const int nw16 = in_sizes[1] / 16;
  prep_w_kernel<<<(nw16 + 255) / 256, 256, 0, stream>>>(qw, (uint4*)w8, nw16);

  dim3 grid(N / 256, M / 256);
  gemm_fp8_kernel<<<grid, 512, 0, stream>>>(qx, w8, wscale, iscale, bias,
                                            out, M, N, K);
}